// Round 1
// baseline (368.304 us; speedup 1.0000x reference)
//
#include <hip/hip_runtime.h>
#include <hip/hip_fp16.h>
#include <math.h>

#define N_NODES 50000
#define N_EDGES 800000
#define IN_C 96
#define HID_C 64
#define OUT_C 40
#define ALPHA 0.2f
#define NEG_SLOPE 0.01f
#define QCAP 131072  // per-partition queue capacity; mean 100k, ~100 sigma margin

// planar half-plane stride (32 halves per row)
#define PLANE_H ((size_t)N_NODES * 32)   // in __half units
#define PLANE_F4 ((size_t)N_NODES * 4)   // in float4 units

typedef _Float16 f16x8 __attribute__((ext_vector_type(8)));
typedef float f32x4 __attribute__((ext_vector_type(4)));

__device__ __forceinline__ int edge_at(const void* ei, int is64, long long pos) {
    return is64 ? (int)((const long long*)ei)[pos] : ((const int*)ei)[pos];
}

// ---------------- zero deg + qtail + edge dtype detect (fused) ----------------
__global__ void zero_detect_k(int* deg, int n, int* qtail, const unsigned int* ei, int* flag) {
    int i = blockIdx.x * blockDim.x + threadIdx.x;
    if (i < n) deg[i] = 0;
    if (i < 8) qtail[i] = 0;
    if (i == 0) {
        int is64 = 1;
        for (int j = 1; j < 16; j += 2)
            if (ei[j] != 0u) is64 = 0;
        *flag = is64;
    }
}

// ---- phase A: one pass over edges. Per 1024-edge tile: LDS rank counters ->
// ONE block-level atomic per partition -> threads write (s,d) at base+rank.
__global__ void bucketA_k(const void* ei, const int* flag, int* __restrict__ deg,
                          int* __restrict__ qtail, int2* __restrict__ queue, int E) {
    __shared__ int cnt[8], qb[8];
    int f = *flag;
    int e0 = blockIdx.x * 1024;
    if (threadIdx.x < 8) cnt[threadIdx.x] = 0;
    __syncthreads();
    int s[4], d[4], p[4], r[4];
    #pragma unroll
    for (int k = 0; k < 4; ++k) {
        int e = e0 + threadIdx.x + k * 256;
        if (e < E) {
            d[k] = edge_at(ei, f, (long long)E + e);
            s[k] = edge_at(ei, f, e);
            atomicAdd(&deg[d[k]], 1);
            p[k] = d[k] / (N_NODES / 8);
            if (p[k] > 7) p[k] = 7;
            r[k] = atomicAdd(&cnt[p[k]], 1);
        } else p[k] = -1;
    }
    __syncthreads();
    if (threadIdx.x < 8) qb[threadIdx.x] = atomicAdd(&qtail[threadIdx.x], cnt[threadIdx.x]);
    __syncthreads();
    #pragma unroll
    for (int k = 0; k < 4; ++k) {
        if (p[k] >= 0) {
            int pos = qb[p[k]] + r[k];
            if (pos < QCAP) queue[(size_t)p[k] * QCAP + pos] = make_int2(s[k], d[k]);
        }
    }
}

// ---- phase B: per-partition streaming read of queue, scatter into the
// L2-resident csrc window (blockIdx%8 = partition ~ XCD).
__global__ void bucketB_k(const int* __restrict__ qtail, const int2* __restrict__ queue,
                          int* __restrict__ cursor, int* __restrict__ csrc) {
    int p = blockIdx.x & 7;
    int j = blockIdx.x >> 3;
    int J = gridDim.x >> 3;
    int n = qtail[p]; if (n > QCAP) n = QCAP;
    const int2* q = queue + (size_t)p * QCAP;
    for (int i = j * blockDim.x + threadIdx.x; i < n; i += J * blockDim.x) {
        int2 e = q[i];
        int pos = atomicAdd(&cursor[e.y], 1);
        csrc[pos] = e.x;
    }
}

// ---- parallel 3-phase exclusive scan over deg[n] ----
__global__ void scan_p1_k(const int* __restrict__ deg, int* __restrict__ part, int n) {
    __shared__ int sm[256];
    int t = threadIdx.x, i = blockIdx.x * 256 + t;
    int v = (i < n) ? deg[i] : 0;
    sm[t] = v;
    __syncthreads();
    for (int off = 1; off < 256; off <<= 1) {
        int u = (t >= off) ? sm[t - off] : 0;
        __syncthreads();
        sm[t] += u;
        __syncthreads();
    }
    if (t == 255) part[blockIdx.x] = sm[255];
}

__global__ void scan_p2_k(int* part, int nb, int* rowptr, int n) {
    __shared__ int sm[256];
    int t = threadIdx.x;
    int v = (t < nb) ? part[t] : 0;
    sm[t] = v;
    __syncthreads();
    for (int off = 1; off < 256; off <<= 1) {
        int u = (t >= off) ? sm[t - off] : 0;
        __syncthreads();
        sm[t] += u;
        __syncthreads();
    }
    if (t < nb) part[t] = sm[t] - v;  // exclusive
    if (t == 255) rowptr[n] = sm[255];
}

// scan_p3 + bucket histogram fused (both consume deg with the same grid)
__global__ void scan_p3_k(const int* __restrict__ deg, const int* __restrict__ part,
                          int* __restrict__ rowptr, int* __restrict__ cursor,
                          float* __restrict__ dinv, int* __restrict__ bcnt, int n) {
    __shared__ int sm[256];
    __shared__ int h[64];
    int t = threadIdx.x, i = blockIdx.x * 256 + t;
    if (t < 64) h[t] = 0;
    int v = (i < n) ? deg[i] : 0;
    sm[t] = v;
    __syncthreads();
    for (int off = 1; off < 256; off <<= 1) {
        int u = (t >= off) ? sm[t - off] : 0;
        __syncthreads();
        sm[t] += u;
        __syncthreads();
    }
    if (i < n) {
        int excl = sm[t] - v + part[blockIdx.x];
        rowptr[i] = excl;
        cursor[i] = excl;
        dinv[i] = rsqrtf((float)v + 1.0f);  // +1 self loop
        int dd = v; if (dd > 63) dd = 63;
        atomicAdd(&h[63 - dd], 1);          // bucket = 63-deg (descending)
    }
    __syncthreads();
    if (t < 64) bcnt[blockIdx.x * 64 + t] = h[t];
}

// bscanA: one block per bucket; parallel exclusive scan over nb block-counts.
__global__ void bscanA_k(const int* __restrict__ bcnt, int* __restrict__ bbase,
                         int* __restrict__ tot, int nb) {
    __shared__ int sm[256];
    int b = blockIdx.x;   // bucket
    int t = threadIdx.x;  // block index within bucket
    int v = (t < nb) ? bcnt[t * 64 + b] : 0;
    sm[t] = v;
    __syncthreads();
    for (int off = 1; off < 256; off <<= 1) {
        int u = (t >= off) ? sm[t - off] : 0;
        __syncthreads();
        sm[t] += u;
        __syncthreads();
    }
    if (t < nb) bbase[t * 64 + b] = sm[t] - v;  // exclusive, per-bucket local
    if (t == 255) tot[b] = sm[255];
}

// perm + bucket-start scan fused (each block redoes the trivial 64-scan)
__global__ void perm_k(const int* __restrict__ deg, const int* __restrict__ bbase,
                       const int* __restrict__ tot, int* __restrict__ perm, int n) {
    __shared__ int h[64], bs[64];
    int t = threadIdx.x, i = blockIdx.x * 256 + t;
    if (t < 64) { h[t] = 0; bs[t] = tot[t]; }
    __syncthreads();
    if (t == 0) {
        int run = 0;
        for (int k = 0; k < 64; ++k) { int v = bs[k]; bs[k] = run; run += v; }
    }
    __syncthreads();
    if (i < n) {
        int d = deg[i]; if (d > 63) d = 63;
        int b = 63 - d;
        int rank = atomicAdd(&h[b], 1);
        perm[bs[b] + bbase[blockIdx.x * 64 + b] + rank] = i;
    }
}

__device__ __forceinline__ void add8(float* acc, float4 v, float w) {
    const __half2* hp = (const __half2*)&v;
    #pragma unroll
    for (int j = 0; j < 4; ++j) {
        float2 f = __half22float2(hp[j]);
        acc[2 * j] += w * f.x;
        acc[2 * j + 1] += w * f.y;
    }
}

// ---------------- C=64 prop, PLANAR-SPLIT: feature buffers stored as two
// 32-channel planes of 3.2 MB each. half = blockIdx parity -> with round-robin
// block->XCD dispatch, each XCD's 4 MB L2 only caches ONE plane -> random
// gathers become L2 hits instead of an L2/L3 mix. 4 lanes x 16 B per node.
template <bool COMBINE, bool LEAKY, bool BIAS>
__global__ void __launch_bounds__(256) prop32_k(
        const int* __restrict__ perm,
        const int* __restrict__ rowptr, const int* __restrict__ csrc,
        const float* __restrict__ dinv,
        const __half* __restrict__ in, const __half* __restrict__ h0,
        const float* __restrict__ bias,
        __half* __restrict__ out, int N) {
    int half = blockIdx.x & 1;
    int g = (blockIdx.x >> 1) * (blockDim.x >> 2) + (threadIdx.x >> 2);
    int ci = threadIdx.x & 3;  // 4 lanes x 8ch = 32 channels (one plane)
    if (g >= N) return;
    int node = perm[g];
    const float4* in4 = (const float4*)in + (size_t)half * PLANE_F4;
    float acc[8];
    {   // self-loop term G[node]
        float4 r = in4[(size_t)node * 4 + ci];
        const __half2* hp = (const __half2*)&r;
        #pragma unroll
        for (int j = 0; j < 4; ++j) {
            float2 f = __half22float2(hp[j]);
            acc[2 * j] = f.x;
            acc[2 * j + 1] = f.y;
        }
    }
    int r0 = rowptr[node], r1 = rowptr[node + 1];
    int i = r0;
    for (; i + 3 < r1; i += 4) {  // 4 rows in flight per group
        int s0 = csrc[i], s1 = csrc[i + 1], s2 = csrc[i + 2], s3 = csrc[i + 3];
        float4 v0 = in4[(size_t)s0 * 4 + ci];
        float4 v1 = in4[(size_t)s1 * 4 + ci];
        float4 v2 = in4[(size_t)s2 * 4 + ci];
        float4 v3 = in4[(size_t)s3 * 4 + ci];
        add8(acc, v0, 1.0f);
        add8(acc, v1, 1.0f);
        add8(acc, v2, 1.0f);
        add8(acc, v3, 1.0f);
    }
    for (; i < r1; ++i) {
        float4 v0 = in4[(size_t)csrc[i] * 4 + ci];
        add8(acc, v0, 1.0f);
    }
    float di = dinv[node];
    float sc = di * di;
    float v[8];
    #pragma unroll
    for (int j = 0; j < 8; ++j) v[j] = sc * acc[j];
    if (BIAS) {  // lane handles channels [32*half + 8*ci, +8)
        float4 b0v = ((const float4*)bias)[half * 8 + 2 * ci];
        float4 b1v = ((const float4*)bias)[half * 8 + 2 * ci + 1];
        v[0] += di * b0v.x; v[1] += di * b0v.y; v[2] += di * b0v.z; v[3] += di * b0v.w;
        v[4] += di * b1v.x; v[5] += di * b1v.y; v[6] += di * b1v.z; v[7] += di * b1v.w;
    }
    if (COMBINE) {
        float4 r = ((const float4*)h0 + (size_t)half * PLANE_F4)[(size_t)node * 4 + ci];
        const __half2* hp = (const __half2*)&r;
        #pragma unroll
        for (int j = 0; j < 4; ++j) {
            float2 f = __half22float2(hp[j]);
            v[2 * j]     = (1.0f - ALPHA) * v[2 * j]     + ALPHA * f.x;
            v[2 * j + 1] = (1.0f - ALPHA) * v[2 * j + 1] + ALPHA * f.y;
        }
    }
    if (LEAKY) {
        #pragma unroll
        for (int j = 0; j < 8; ++j) v[j] = v[j] > 0.0f ? v[j] : NEG_SLOPE * v[j];
    }
    float4 o;
    __half2* op = (__half2*)&o;
    #pragma unroll
    for (int j = 0; j < 4; ++j)
        op[j] = __float22half2_rn(make_float2(v[2 * j], v[2 * j + 1]));
    ((float4*)out + (size_t)half * PLANE_F4)[(size_t)node * 4 + ci] = o;
}

// ---------------- C=40 prop: 8-lane group per node, 5 active lanes x float4.
// One wave VMEM instr now gathers 8 rows x 80 B (was 2 rows at half2/lane).
__global__ void __launch_bounds__(256) prop40_k(
        const int* __restrict__ perm,
        const int* __restrict__ rowptr, const int* __restrict__ csrc,
        const float* __restrict__ dinv,
        const __half* __restrict__ in, __half* __restrict__ out, int N) {
    int g = blockIdx.x * (blockDim.x >> 3) + (threadIdx.x >> 3);
    int ci = threadIdx.x & 7;
    if (g >= N) return;
    int node = perm[g];
    bool act = ci < 5;  // 5 lanes x 8ch = 40 channels
    const float4* in4 = (const float4*)in;  // row = 5 float4 (80 B)
    float acc[8] = {0.f, 0.f, 0.f, 0.f, 0.f, 0.f, 0.f, 0.f};
    if (act) {
        float4 r = in4[(size_t)node * 5 + ci];
        const __half2* hp = (const __half2*)&r;
        #pragma unroll
        for (int j = 0; j < 4; ++j) {
            float2 f = __half22float2(hp[j]);
            acc[2 * j] = f.x;
            acc[2 * j + 1] = f.y;
        }
    }
    int r0 = rowptr[node], r1 = rowptr[node + 1];
    int i = r0;
    for (; i + 3 < r1; i += 4) {
        int s0 = csrc[i], s1 = csrc[i + 1], s2 = csrc[i + 2], s3 = csrc[i + 3];
        if (act) {
            float4 v0 = in4[(size_t)s0 * 5 + ci];
            float4 v1 = in4[(size_t)s1 * 5 + ci];
            float4 v2 = in4[(size_t)s2 * 5 + ci];
            float4 v3 = in4[(size_t)s3 * 5 + ci];
            add8(acc, v0, 1.0f);
            add8(acc, v1, 1.0f);
            add8(acc, v2, 1.0f);
            add8(acc, v3, 1.0f);
        }
    }
    for (; i < r1; ++i) {
        int s0 = csrc[i];
        if (act) {
            float4 v0 = in4[(size_t)s0 * 5 + ci];
            add8(acc, v0, 1.0f);
        }
    }
    if (act) {
        float di = dinv[node];
        float sc = di * di;
        float4 o;
        __half2* op = (__half2*)&o;
        #pragma unroll
        for (int j = 0; j < 4; ++j)
            op[j] = __float22half2_rn(make_float2(sc * acc[2 * j], sc * acc[2 * j + 1]));
        ((float4*)out)[(size_t)node * 5 + ci] = o;
    }
}

// ---------------- final C=40 prop + b4 + log_softmax fused, fp32 out -----------
__global__ void __launch_bounds__(256) prop40_softmax_k(
        const int* __restrict__ perm,
        const int* __restrict__ rowptr, const int* __restrict__ csrc,
        const float* __restrict__ dinv,
        const __half* __restrict__ in, const float* __restrict__ bias,
        float* __restrict__ out, int N) {
    int g = blockIdx.x * (blockDim.x >> 3) + (threadIdx.x >> 3);
    int ci = threadIdx.x & 7;
    if (g >= N) return;
    int node = perm[g];
    bool act = ci < 5;
    const float4* in4 = (const float4*)in;
    float acc[8] = {0.f, 0.f, 0.f, 0.f, 0.f, 0.f, 0.f, 0.f};
    if (act) {
        float4 r = in4[(size_t)node * 5 + ci];
        const __half2* hp = (const __half2*)&r;
        #pragma unroll
        for (int j = 0; j < 4; ++j) {
            float2 f = __half22float2(hp[j]);
            acc[2 * j] = f.x;
            acc[2 * j + 1] = f.y;
        }
    }
    int r0 = rowptr[node], r1 = rowptr[node + 1];
    int i = r0;
    for (; i + 3 < r1; i += 4) {
        int s0 = csrc[i], s1 = csrc[i + 1], s2 = csrc[i + 2], s3 = csrc[i + 3];
        if (act) {
            float4 v0 = in4[(size_t)s0 * 5 + ci];
            float4 v1 = in4[(size_t)s1 * 5 + ci];
            float4 v2 = in4[(size_t)s2 * 5 + ci];
            float4 v3 = in4[(size_t)s3 * 5 + ci];
            add8(acc, v0, 1.0f);
            add8(acc, v1, 1.0f);
            add8(acc, v2, 1.0f);
            add8(acc, v3, 1.0f);
        }
    }
    for (; i < r1; ++i) {
        int s0 = csrc[i];
        if (act) {
            float4 v0 = in4[(size_t)s0 * 5 + ci];
            add8(acc, v0, 1.0f);
        }
    }
    float di = dinv[node];
    float v[8];
    if (act) {
        float4 b0v = ((const float4*)bias)[2 * ci];
        float4 b1v = ((const float4*)bias)[2 * ci + 1];
        v[0] = di * acc[0] + b0v.x; v[1] = di * acc[1] + b0v.y;
        v[2] = di * acc[2] + b0v.z; v[3] = di * acc[3] + b0v.w;
        v[4] = di * acc[4] + b1v.x; v[5] = di * acc[5] + b1v.y;
        v[6] = di * acc[6] + b1v.z; v[7] = di * acc[7] + b1v.w;
    } else {
        #pragma unroll
        for (int j = 0; j < 8; ++j) v[j] = -INFINITY;
    }
    float m = v[0];
    #pragma unroll
    for (int j = 1; j < 8; ++j) m = fmaxf(m, v[j]);
    #pragma unroll
    for (int off = 4; off >= 1; off >>= 1) m = fmaxf(m, __shfl_xor(m, off));
    float e = 0.0f;
    if (act) {
        #pragma unroll
        for (int j = 0; j < 8; ++j) e += expf(v[j] - m);
    }
    #pragma unroll
    for (int off = 4; off >= 1; off >>= 1) e += __shfl_xor(e, off);
    float ls = m + logf(e);
    if (act) {
        float4 o0 = make_float4(v[0] - ls, v[1] - ls, v[2] - ls, v[3] - ls);
        float4 o1 = make_float4(v[4] - ls, v[5] - ls, v[6] - ls, v[7] - ls);
        ((float4*)out)[(size_t)node * 10 + 2 * ci] = o0;
        ((float4*)out)[(size_t)node * 10 + 2 * ci + 1] = o1;
    }
}

// ---------------- MFMA dense linear: out[m,o] = sum_k in[m,k]*W[o,k] -----------
// PIN: input is the planar-split fp16 layout (two N x 32 planes, K must be 64).
// POUT: output written to planar-split layout (O must be 64).
template <int O, int K, bool FP32IN, bool SCALE, bool PIN, bool POUT>
__global__ void __launch_bounds__(256) mfma_lin_k(const void* __restrict__ in_,
                                                  const float* __restrict__ W,
                                                  const float* __restrict__ dinv,
                                                  __half* __restrict__ out, int Mtiles) {
    constexpr int P2 = 52;  // half2 pitch (104 halves = 208 B rows, 16B-aligned)
    __shared__ __half2 wsh[O * P2];
    for (int idx = threadIdx.x; idx < O * (K / 2); idx += 256) {
        int o = idx / (K / 2), kk = idx - o * (K / 2);
        float2 w2 = ((const float2*)W)[o * (K / 2) + kk];
        wsh[o * P2 + kk] = __floats2half2_rn(w2.x, w2.y);
    }
    __syncthreads();
    int wave = (blockIdx.x * 256 + threadIdx.x) >> 6;
    if (wave >= Mtiles) return;
    int lane = threadIdx.x & 63;
    int lm = lane & 15, q = lane >> 4;
    long long m0 = (long long)wave * 16;
    constexpr int NT = (O + 15) / 16;
    f32x4 acc[NT];
    #pragma unroll
    for (int j = 0; j < NT; ++j) acc[j] = (f32x4){0.f, 0.f, 0.f, 0.f};
    const __half* wsp = (const __half*)wsh;
    #pragma unroll
    for (int k0 = 0; k0 < K; k0 += 32) {
        f16x8 a;
        if (FP32IN) {
            const float* xr = (const float*)in_ + (m0 + lm) * K + k0 + q * 8;
            float4 x0 = ((const float4*)xr)[0];
            float4 x1 = ((const float4*)xr)[1];
            a = (f16x8){(_Float16)x0.x, (_Float16)x0.y, (_Float16)x0.z, (_Float16)x0.w,
                        (_Float16)x1.x, (_Float16)x1.y, (_Float16)x1.z, (_Float16)x1.w};
        } else if (PIN) {
            // planar: k-channel (k0+q*8 .. +8) lives in plane k0>>5 at inner q*8
            const __half* xr = (const __half*)in_ + (size_t)(k0 >> 5) * PLANE_H
                               + (m0 + lm) * 32 + q * 8;
            a = *(const f16x8*)xr;
        } else {
            const __half* xr = (const __half*)in_ + (m0 + lm) * K + k0 + q * 8;
            a = *(const f16x8*)xr;
        }
        #pragma unroll
        for (int j = 0; j < NT; ++j) {
            f16x8 b = *(const f16x8*)(wsp + (16 * j + lm) * (2 * P2) + k0 + q * 8);
            acc[j] = __builtin_amdgcn_mfma_f32_16x16x32_f16(a, b, acc[j], 0, 0, 0);
        }
    }
    #pragma unroll
    for (int r = 0; r < 4; ++r) {
        long long m = m0 + q * 4 + r;
        float sc = SCALE ? dinv[m] : 1.0f;
        #pragma unroll
        for (int j = 0; j < NT; ++j) {
            int col = 16 * j + lm;
            if (POUT) {
                out[(size_t)(col >> 5) * PLANE_H + m * 32 + (col & 31)] =
                    __float2half(acc[j][r] * sc);
            } else if (col < O) {
                out[m * O + col] = __float2half(acc[j][r] * sc);
            }
        }
    }
}

// ---------------- launcher ----------------
static inline int cdiv(long long a, long long b) { return (int)((a + b - 1) / b); }
static inline size_t align256(size_t x) { return (x + 255) & ~(size_t)255; }

extern "C" void kernel_launch(void* const* d_in, const int* in_sizes, int n_in,
                              void* d_out, int out_size, void* d_ws, size_t ws_size,
                              hipStream_t stream) {
    const float* x  = (const float*)d_in[0];
    const void*  ei = d_in[1];
    const float* W0 = (const float*)d_in[2];
    const float* b0 = (const float*)d_in[3];
    const float* W4 = (const float*)d_in[4];
    const float* b4 = (const float*)d_in[5];
    float* out = (float*)d_out;

    const int N = N_NODES, E = N_EDGES;
    const int NB = cdiv(N, 256);  // 196
    char* ws = (char*)d_ws;
    int*    flag   = (int*)ws;     ws += 256;
    int*    deg    = (int*)ws;     ws += align256((size_t)N * 4);
    int*    rowptr = (int*)ws;     ws += align256((size_t)(N + 1) * 4);
    int*    cursor = (int*)ws;     ws += align256((size_t)N * 4);
    int*    part   = (int*)ws;     ws += align256(256 * 4);
    int*    bcnt   = (int*)ws;     ws += align256((size_t)NB * 64 * 4);
    int*    bbase  = (int*)ws;     ws += align256((size_t)NB * 64 * 4);
    int*    tot    = (int*)ws;     ws += align256(64 * 4);
    int*    qtail  = (int*)ws;     ws += align256(8 * 4);
    int*    perm   = (int*)ws;     ws += align256((size_t)N * 4);
    float*  dinv   = (float*)ws;   ws += align256((size_t)N * 4);
    int*    csrc   = (int*)ws;     ws += align256((size_t)E * 4);
    int2*   queue  = (int2*)ws;    ws += align256((size_t)8 * QCAP * 8);
    __half* bufA   = (__half*)ws;  ws += align256((size_t)N * HID_C * 2);
    __half* bufB   = (__half*)ws;  ws += align256((size_t)N * HID_C * 2);
    __half* bufC   = (__half*)ws;  ws += align256((size_t)N * HID_C * 2);

    const int T = 256;
    const int MT = N / 16;              // 3125 MFMA tiles
    const int LB = cdiv(MT, 4);         // mfma_lin blocks (4 waves each)
    const int P32B = 2 * cdiv(N, T / 4);  // prop32 blocks: 2 halves x 64 groups/blk
    const int P40B = cdiv(N, T / 8);      // prop40 blocks (32 groups each)

    // ---- CSR build (two-phase partition queues) + degree sort ----
    zero_detect_k<<<cdiv(N, T), T, 0, stream>>>(deg, N, qtail, (const unsigned int*)ei, flag);
    bucketA_k<<<cdiv(E, 1024), T, 0, stream>>>(ei, flag, deg, qtail, queue, E);
    scan_p1_k<<<NB, 256, 0, stream>>>(deg, part, N);
    scan_p2_k<<<1, 256, 0, stream>>>(part, NB, rowptr, N);
    scan_p3_k<<<NB, 256, 0, stream>>>(deg, part, rowptr, cursor, dinv, bcnt, N);
    bscanA_k<<<64, 256, 0, stream>>>(bcnt, bbase, tot, NB);
    perm_k<<<NB, 256, 0, stream>>>(deg, bbase, tot, perm, N);
    bucketB_k<<<8 * 64, T, 0, stream>>>(qtail, queue, cursor, csrc);

    // ---- conv0 (SGConv, K=2): linear folded first; output G-space (planar) ----
    mfma_lin_k<HID_C, IN_C, true, true, false, true><<<LB, 256, 0, stream>>>(
        x, W0, dinv, bufA, MT);
    prop32_k<false, false, false><<<P32B, T, 0, stream>>>(
        perm, rowptr, csrc, dinv, bufA, nullptr, nullptr, bufB, N);
    prop32_k<false, false, true><<<P32B, T, 0, stream>>>(
        perm, rowptr, csrc, dinv, bufB, nullptr, b0, bufC, N);  // + dinv*b0 -> Gh0

    // ---- conv1..conv3: leaky(APPNP(h)) entirely in G-space, Gh0 = bufC ----
    for (int r = 0; r < 3; ++r) {
        prop32_k<true, false, false><<<P32B, T, 0, stream>>>(
            perm, rowptr, csrc, dinv, bufC, bufC, nullptr, bufB, N);
        // in-place bufC write safe: Gh0[node] read only by the group writing it
        prop32_k<true, true, false><<<P32B, T, 0, stream>>>(
            perm, rowptr, csrc, dinv, bufB, bufC, nullptr, bufC, N);
    }

    // ---- conv4 (SGConv, K=2): G-space lin (no scale), then 2 hops at 40ch ----
    mfma_lin_k<OUT_C, HID_C, false, false, true, false><<<LB, 256, 0, stream>>>(
        bufC, W4, dinv, bufA, MT);
    prop40_k<<<P40B, T, 0, stream>>>(perm, rowptr, csrc, dinv, bufA, bufB, N);
    prop40_softmax_k<<<P40B, T, 0, stream>>>(perm, rowptr, csrc, dinv, bufB, b4, out, N);
}

// Round 2
// 333.926 us; speedup vs baseline: 1.1030x; 1.1030x over previous
//
#include <hip/hip_runtime.h>
#include <hip/hip_fp16.h>
#include <math.h>

#define N_NODES 50000
#define N_EDGES 800000
#define IN_C 96
#define HID_C 64
#define OUT_C 40
#define ALPHA 0.2f
#define NEG_SLOPE 0.01f
#define QCAP 131072  // per-partition queue capacity; mean 100k, ~100 sigma margin

typedef _Float16 f16x8 __attribute__((ext_vector_type(8)));
typedef float f32x4 __attribute__((ext_vector_type(4)));

__device__ __forceinline__ int edge_at(const void* ei, int is64, long long pos) {
    return is64 ? (int)((const long long*)ei)[pos] : ((const int*)ei)[pos];
}

// ---------------- zero deg + qtail + edge dtype detect (fused) ----------------
__global__ void zero_detect_k(int* deg, int n, int* qtail, const unsigned int* ei, int* flag) {
    int i = blockIdx.x * blockDim.x + threadIdx.x;
    if (i < n) deg[i] = 0;
    if (i < 8) qtail[i] = 0;
    if (i == 0) {
        int is64 = 1;
        for (int j = 1; j < 16; j += 2)
            if (ei[j] != 0u) is64 = 0;
        *flag = is64;
    }
}

// ---- phase A: one pass over edges. Per 1024-edge tile: LDS rank counters ->
// ONE block-level atomic per partition -> threads write (s,d) at base+rank.
__global__ void bucketA_k(const void* ei, const int* flag, int* __restrict__ deg,
                          int* __restrict__ qtail, int2* __restrict__ queue, int E) {
    __shared__ int cnt[8], qb[8];
    int f = *flag;
    int e0 = blockIdx.x * 1024;
    if (threadIdx.x < 8) cnt[threadIdx.x] = 0;
    __syncthreads();
    int s[4], d[4], p[4], r[4];
    #pragma unroll
    for (int k = 0; k < 4; ++k) {
        int e = e0 + threadIdx.x + k * 256;
        if (e < E) {
            d[k] = edge_at(ei, f, (long long)E + e);
            s[k] = edge_at(ei, f, e);
            atomicAdd(&deg[d[k]], 1);
            p[k] = d[k] / (N_NODES / 8);
            if (p[k] > 7) p[k] = 7;
            r[k] = atomicAdd(&cnt[p[k]], 1);
        } else p[k] = -1;
    }
    __syncthreads();
    if (threadIdx.x < 8) qb[threadIdx.x] = atomicAdd(&qtail[threadIdx.x], cnt[threadIdx.x]);
    __syncthreads();
    #pragma unroll
    for (int k = 0; k < 4; ++k) {
        if (p[k] >= 0) {
            int pos = qb[p[k]] + r[k];
            if (pos < QCAP) queue[(size_t)p[k] * QCAP + pos] = make_int2(s[k], d[k]);
        }
    }
}

// ---- phase B: per-partition streaming read of queue, scatter into the
// L2-resident csrc window (blockIdx%8 = partition ~ XCD).
__global__ void bucketB_k(const int* __restrict__ qtail, const int2* __restrict__ queue,
                          int* __restrict__ cursor, int* __restrict__ csrc) {
    int p = blockIdx.x & 7;
    int j = blockIdx.x >> 3;
    int J = gridDim.x >> 3;
    int n = qtail[p]; if (n > QCAP) n = QCAP;
    const int2* q = queue + (size_t)p * QCAP;
    for (int i = j * blockDim.x + threadIdx.x; i < n; i += J * blockDim.x) {
        int2 e = q[i];
        int pos = atomicAdd(&cursor[e.y], 1);
        csrc[pos] = e.x;
    }
}

// ---- parallel 3-phase exclusive scan over deg[n] ----
__global__ void scan_p1_k(const int* __restrict__ deg, int* __restrict__ part, int n) {
    __shared__ int sm[256];
    int t = threadIdx.x, i = blockIdx.x * 256 + t;
    int v = (i < n) ? deg[i] : 0;
    sm[t] = v;
    __syncthreads();
    for (int off = 1; off < 256; off <<= 1) {
        int u = (t >= off) ? sm[t - off] : 0;
        __syncthreads();
        sm[t] += u;
        __syncthreads();
    }
    if (t == 255) part[blockIdx.x] = sm[255];
}

__global__ void scan_p2_k(int* part, int nb, int* rowptr, int n) {
    __shared__ int sm[256];
    int t = threadIdx.x;
    int v = (t < nb) ? part[t] : 0;
    sm[t] = v;
    __syncthreads();
    for (int off = 1; off < 256; off <<= 1) {
        int u = (t >= off) ? sm[t - off] : 0;
        __syncthreads();
        sm[t] += u;
        __syncthreads();
    }
    if (t < nb) part[t] = sm[t] - v;  // exclusive
    if (t == 255) rowptr[n] = sm[255];
}

// scan_p3 + bucket histogram fused (both consume deg with the same grid)
__global__ void scan_p3_k(const int* __restrict__ deg, const int* __restrict__ part,
                          int* __restrict__ rowptr, int* __restrict__ cursor,
                          float* __restrict__ dinv, int* __restrict__ bcnt, int n) {
    __shared__ int sm[256];
    __shared__ int h[64];
    int t = threadIdx.x, i = blockIdx.x * 256 + t;
    if (t < 64) h[t] = 0;
    int v = (i < n) ? deg[i] : 0;
    sm[t] = v;
    __syncthreads();
    for (int off = 1; off < 256; off <<= 1) {
        int u = (t >= off) ? sm[t - off] : 0;
        __syncthreads();
        sm[t] += u;
        __syncthreads();
    }
    if (i < n) {
        int excl = sm[t] - v + part[blockIdx.x];
        rowptr[i] = excl;
        cursor[i] = excl;
        dinv[i] = rsqrtf((float)v + 1.0f);  // +1 self loop
        int dd = v; if (dd > 63) dd = 63;
        atomicAdd(&h[63 - dd], 1);          // bucket = 63-deg (descending)
    }
    __syncthreads();
    if (t < 64) bcnt[blockIdx.x * 64 + t] = h[t];
}

// bscanA: one block per bucket; parallel exclusive scan over nb block-counts.
__global__ void bscanA_k(const int* __restrict__ bcnt, int* __restrict__ bbase,
                         int* __restrict__ tot, int nb) {
    __shared__ int sm[256];
    int b = blockIdx.x;   // bucket
    int t = threadIdx.x;  // block index within bucket
    int v = (t < nb) ? bcnt[t * 64 + b] : 0;
    sm[t] = v;
    __syncthreads();
    for (int off = 1; off < 256; off <<= 1) {
        int u = (t >= off) ? sm[t - off] : 0;
        __syncthreads();
        sm[t] += u;
        __syncthreads();
    }
    if (t < nb) bbase[t * 64 + b] = sm[t] - v;  // exclusive, per-bucket local
    if (t == 255) tot[b] = sm[255];
}

// perm + bucket-start scan fused (each block redoes the trivial 64-scan)
__global__ void perm_k(const int* __restrict__ deg, const int* __restrict__ bbase,
                       const int* __restrict__ tot, int* __restrict__ perm, int n) {
    __shared__ int h[64], bs[64];
    int t = threadIdx.x, i = blockIdx.x * 256 + t;
    if (t < 64) { h[t] = 0; bs[t] = tot[t]; }
    __syncthreads();
    if (t == 0) {
        int run = 0;
        for (int k = 0; k < 64; ++k) { int v = bs[k]; bs[k] = run; run += v; }
    }
    __syncthreads();
    if (i < n) {
        int d = deg[i]; if (d > 63) d = 63;
        int b = 63 - d;
        int rank = atomicAdd(&h[b], 1);
        perm[bs[b] + bbase[blockIdx.x * 64 + b] + rank] = i;
    }
}

// ---------------- C=64 prop: 8-lane group per NODE (degree-sorted) -------------
// Lane ci owns channels [8ci,8ci+8) (16 B of the 128 B row) end-to-end.
// 8-deep software pipeline: 8 row-gathers in flight while the NEXT batch's
// csrc indices load (hides the idx->gather dependency chain). Latency-bound
// regime (3.8 TB/s eff << 34.5 TB/s L2) -> MLP is the lever.
__device__ __forceinline__ void add8(float* acc, float4 v, float w) {
    const __half2* hp = (const __half2*)&v;
    #pragma unroll
    for (int j = 0; j < 4; ++j) {
        float2 f = __half22float2(hp[j]);
        acc[2 * j] += w * f.x;
        acc[2 * j + 1] += w * f.y;
    }
}

template <bool COMBINE, bool LEAKY, bool BIAS>
__global__ void __launch_bounds__(256) prop64_k(
        const int* __restrict__ perm,
        const int* __restrict__ rowptr, const int* __restrict__ csrc,
        const float* __restrict__ dinv,
        const __half* __restrict__ in, const __half* __restrict__ h0,
        const float* __restrict__ bias,
        __half* __restrict__ out, int N) {
    int g = blockIdx.x * (blockDim.x >> 3) + (threadIdx.x >> 3);
    int ci = threadIdx.x & 7;  // 8 lanes x 8ch = 64 channels
    if (g >= N) return;
    int node = perm[g];
    const float4* in8 = (const float4*)in;  // 16 B = 8 halves (bit-carrier)
    float acc[8];
    {   // self-loop term G[node]
        float4 r = in8[node * 8 + ci];
        const __half2* hp = (const __half2*)&r;
        #pragma unroll
        for (int j = 0; j < 4; ++j) {
            float2 f = __half22float2(hp[j]);
            acc[2 * j] = f.x;
            acc[2 * j + 1] = f.y;
        }
    }
    int r0 = rowptr[node], r1 = rowptr[node + 1];
    int i = r0;
    int s[8];
    if (i + 7 < r1) {
        #pragma unroll
        for (int j = 0; j < 8; ++j) s[j] = csrc[i + j];
    }
    for (; i + 15 < r1; i += 8) {  // steady state: 8 gathers + next-batch idx in flight
        float4 v[8];
        #pragma unroll
        for (int j = 0; j < 8; ++j) v[j] = in8[(size_t)s[j] * 8 + ci];
        #pragma unroll
        for (int j = 0; j < 8; ++j) s[j] = csrc[i + 8 + j];
        #pragma unroll
        for (int j = 0; j < 8; ++j) add8(acc, v[j], 1.0f);
    }
    if (i + 7 < r1) {  // drain the preloaded batch
        float4 v[8];
        #pragma unroll
        for (int j = 0; j < 8; ++j) v[j] = in8[(size_t)s[j] * 8 + ci];
        #pragma unroll
        for (int j = 0; j < 8; ++j) add8(acc, v[j], 1.0f);
        i += 8;
    }
    for (; i + 3 < r1; i += 4) {
        int s0 = csrc[i], s1 = csrc[i + 1], s2 = csrc[i + 2], s3 = csrc[i + 3];
        float4 v0 = in8[(size_t)s0 * 8 + ci];
        float4 v1 = in8[(size_t)s1 * 8 + ci];
        float4 v2 = in8[(size_t)s2 * 8 + ci];
        float4 v3 = in8[(size_t)s3 * 8 + ci];
        add8(acc, v0, 1.0f);
        add8(acc, v1, 1.0f);
        add8(acc, v2, 1.0f);
        add8(acc, v3, 1.0f);
    }
    for (; i < r1; ++i) {
        float4 v0 = in8[(size_t)csrc[i] * 8 + ci];
        add8(acc, v0, 1.0f);
    }
    float di = dinv[node];
    float sc = di * di;
    float v[8];
    #pragma unroll
    for (int j = 0; j < 8; ++j) v[j] = sc * acc[j];
    if (BIAS) {
        float4 b0v = ((const float4*)bias)[2 * ci];
        float4 b1v = ((const float4*)bias)[2 * ci + 1];
        v[0] += di * b0v.x; v[1] += di * b0v.y; v[2] += di * b0v.z; v[3] += di * b0v.w;
        v[4] += di * b1v.x; v[5] += di * b1v.y; v[6] += di * b1v.z; v[7] += di * b1v.w;
    }
    if (COMBINE) {
        float4 r = ((const float4*)h0)[node * 8 + ci];
        const __half2* hp = (const __half2*)&r;
        #pragma unroll
        for (int j = 0; j < 4; ++j) {
            float2 f = __half22float2(hp[j]);
            v[2 * j]     = (1.0f - ALPHA) * v[2 * j]     + ALPHA * f.x;
            v[2 * j + 1] = (1.0f - ALPHA) * v[2 * j + 1] + ALPHA * f.y;
        }
    }
    if (LEAKY) {
        #pragma unroll
        for (int j = 0; j < 8; ++j) v[j] = v[j] > 0.0f ? v[j] : NEG_SLOPE * v[j];
    }
    float4 o;
    __half2* op = (__half2*)&o;
    #pragma unroll
    for (int j = 0; j < 4; ++j)
        op[j] = __float22half2_rn(make_float2(v[2 * j], v[2 * j + 1]));
    ((float4*)out)[node * 8 + ci] = o;
}

// ---------------- C=40 prop, PADDED to 128 B rows (pitch 64 halves) ------------
// 8-lane group per node, lanes 0..4 own 8 channels each; lanes 5..7 clamp to
// lane 0's slot (no divergence in the gather loop; junk never stored). Padding
// makes every row exactly ONE 128 B cache line (80 B rows straddle 50%).
__global__ void __launch_bounds__(256) prop40_k(
        const int* __restrict__ perm,
        const int* __restrict__ rowptr, const int* __restrict__ csrc,
        const float* __restrict__ dinv,
        const __half* __restrict__ in, __half* __restrict__ out, int N) {
    int g = blockIdx.x * (blockDim.x >> 3) + (threadIdx.x >> 3);
    int ci = threadIdx.x & 7;
    if (g >= N) return;
    int node = perm[g];
    bool act = ci < 5;  // 5 lanes x 8ch = 40 channels
    int cc = act ? ci : 0;
    const float4* in4 = (const float4*)in;  // row = 8 float4 (128 B padded)
    float acc[8];
    {
        float4 r = in4[(size_t)node * 8 + cc];
        const __half2* hp = (const __half2*)&r;
        #pragma unroll
        for (int j = 0; j < 4; ++j) {
            float2 f = __half22float2(hp[j]);
            acc[2 * j] = f.x;
            acc[2 * j + 1] = f.y;
        }
    }
    int r0 = rowptr[node], r1 = rowptr[node + 1];
    int i = r0;
    int s[8];
    if (i + 7 < r1) {
        #pragma unroll
        for (int j = 0; j < 8; ++j) s[j] = csrc[i + j];
    }
    for (; i + 15 < r1; i += 8) {
        float4 v[8];
        #pragma unroll
        for (int j = 0; j < 8; ++j) v[j] = in4[(size_t)s[j] * 8 + cc];
        #pragma unroll
        for (int j = 0; j < 8; ++j) s[j] = csrc[i + 8 + j];
        #pragma unroll
        for (int j = 0; j < 8; ++j) add8(acc, v[j], 1.0f);
    }
    if (i + 7 < r1) {
        float4 v[8];
        #pragma unroll
        for (int j = 0; j < 8; ++j) v[j] = in4[(size_t)s[j] * 8 + cc];
        #pragma unroll
        for (int j = 0; j < 8; ++j) add8(acc, v[j], 1.0f);
        i += 8;
    }
    for (; i + 3 < r1; i += 4) {
        int s0 = csrc[i], s1 = csrc[i + 1], s2 = csrc[i + 2], s3 = csrc[i + 3];
        float4 v0 = in4[(size_t)s0 * 8 + cc];
        float4 v1 = in4[(size_t)s1 * 8 + cc];
        float4 v2 = in4[(size_t)s2 * 8 + cc];
        float4 v3 = in4[(size_t)s3 * 8 + cc];
        add8(acc, v0, 1.0f);
        add8(acc, v1, 1.0f);
        add8(acc, v2, 1.0f);
        add8(acc, v3, 1.0f);
    }
    for (; i < r1; ++i) {
        float4 v0 = in4[(size_t)csrc[i] * 8 + cc];
        add8(acc, v0, 1.0f);
    }
    if (act) {
        float di = dinv[node];
        float sc = di * di;
        float4 o;
        __half2* op = (__half2*)&o;
        #pragma unroll
        for (int j = 0; j < 4; ++j)
            op[j] = __float22half2_rn(make_float2(sc * acc[2 * j], sc * acc[2 * j + 1]));
        ((float4*)out)[(size_t)node * 8 + ci] = o;
    }
}

// ---------------- final C=40 prop + b4 + log_softmax fused, fp32 out -----------
__global__ void __launch_bounds__(256) prop40_softmax_k(
        const int* __restrict__ perm,
        const int* __restrict__ rowptr, const int* __restrict__ csrc,
        const float* __restrict__ dinv,
        const __half* __restrict__ in, const float* __restrict__ bias,
        float* __restrict__ out, int N) {
    int g = blockIdx.x * (blockDim.x >> 3) + (threadIdx.x >> 3);
    int ci = threadIdx.x & 7;
    if (g >= N) return;
    int node = perm[g];
    bool act = ci < 5;
    int cc = act ? ci : 0;
    const float4* in4 = (const float4*)in;  // padded pitch 8 float4
    float acc[8];
    {
        float4 r = in4[(size_t)node * 8 + cc];
        const __half2* hp = (const __half2*)&r;
        #pragma unroll
        for (int j = 0; j < 4; ++j) {
            float2 f = __half22float2(hp[j]);
            acc[2 * j] = f.x;
            acc[2 * j + 1] = f.y;
        }
    }
    int r0 = rowptr[node], r1 = rowptr[node + 1];
    int i = r0;
    int s[8];
    if (i + 7 < r1) {
        #pragma unroll
        for (int j = 0; j < 8; ++j) s[j] = csrc[i + j];
    }
    for (; i + 15 < r1; i += 8) {
        float4 v[8];
        #pragma unroll
        for (int j = 0; j < 8; ++j) v[j] = in4[(size_t)s[j] * 8 + cc];
        #pragma unroll
        for (int j = 0; j < 8; ++j) s[j] = csrc[i + 8 + j];
        #pragma unroll
        for (int j = 0; j < 8; ++j) add8(acc, v[j], 1.0f);
    }
    if (i + 7 < r1) {
        float4 v[8];
        #pragma unroll
        for (int j = 0; j < 8; ++j) v[j] = in4[(size_t)s[j] * 8 + cc];
        #pragma unroll
        for (int j = 0; j < 8; ++j) add8(acc, v[j], 1.0f);
        i += 8;
    }
    for (; i + 3 < r1; i += 4) {
        int s0 = csrc[i], s1 = csrc[i + 1], s2 = csrc[i + 2], s3 = csrc[i + 3];
        float4 v0 = in4[(size_t)s0 * 8 + cc];
        float4 v1 = in4[(size_t)s1 * 8 + cc];
        float4 v2 = in4[(size_t)s2 * 8 + cc];
        float4 v3 = in4[(size_t)s3 * 8 + cc];
        add8(acc, v0, 1.0f);
        add8(acc, v1, 1.0f);
        add8(acc, v2, 1.0f);
        add8(acc, v3, 1.0f);
    }
    for (; i < r1; ++i) {
        float4 v0 = in4[(size_t)csrc[i] * 8 + cc];
        add8(acc, v0, 1.0f);
    }
    float di = dinv[node];
    float v[8];
    if (act) {
        float4 b0v = ((const float4*)bias)[2 * ci];
        float4 b1v = ((const float4*)bias)[2 * ci + 1];
        v[0] = di * acc[0] + b0v.x; v[1] = di * acc[1] + b0v.y;
        v[2] = di * acc[2] + b0v.z; v[3] = di * acc[3] + b0v.w;
        v[4] = di * acc[4] + b1v.x; v[5] = di * acc[5] + b1v.y;
        v[6] = di * acc[6] + b1v.z; v[7] = di * acc[7] + b1v.w;
    } else {
        #pragma unroll
        for (int j = 0; j < 8; ++j) v[j] = -INFINITY;
    }
    float m = v[0];
    #pragma unroll
    for (int j = 1; j < 8; ++j) m = fmaxf(m, v[j]);
    #pragma unroll
    for (int off = 4; off >= 1; off >>= 1) m = fmaxf(m, __shfl_xor(m, off));
    float e = 0.0f;
    if (act) {
        #pragma unroll
        for (int j = 0; j < 8; ++j) e += expf(v[j] - m);
    }
    #pragma unroll
    for (int off = 4; off >= 1; off >>= 1) e += __shfl_xor(e, off);
    float ls = m + logf(e);
    if (act) {
        float4 o0 = make_float4(v[0] - ls, v[1] - ls, v[2] - ls, v[3] - ls);
        float4 o1 = make_float4(v[4] - ls, v[5] - ls, v[6] - ls, v[7] - ls);
        ((float4*)out)[(size_t)node * 10 + 2 * ci] = o0;
        ((float4*)out)[(size_t)node * 10 + 2 * ci + 1] = o1;
    }
}

// ---------------- MFMA dense linear: out[m,o] = sum_k in[m,k]*W[o,k] -----------
// OP = output row pitch in halves (OP=64 pads the 40-ch output to 128 B rows).
template <int O, int K, int OP, bool FP32IN, bool SCALE>
__global__ void __launch_bounds__(256) mfma_lin_k(const void* __restrict__ in_,
                                                  const float* __restrict__ W,
                                                  const float* __restrict__ dinv,
                                                  __half* __restrict__ out, int Mtiles) {
    constexpr int P2 = 52;  // half2 pitch (104 halves = 208 B rows, 16B-aligned)
    __shared__ __half2 wsh[O * P2];
    for (int idx = threadIdx.x; idx < O * (K / 2); idx += 256) {
        int o = idx / (K / 2), kk = idx - o * (K / 2);
        float2 w2 = ((const float2*)W)[o * (K / 2) + kk];
        wsh[o * P2 + kk] = __floats2half2_rn(w2.x, w2.y);
    }
    __syncthreads();
    int wave = (blockIdx.x * 256 + threadIdx.x) >> 6;
    if (wave >= Mtiles) return;
    int lane = threadIdx.x & 63;
    int lm = lane & 15, q = lane >> 4;
    long long m0 = (long long)wave * 16;
    constexpr int NT = (O + 15) / 16;
    f32x4 acc[NT];
    #pragma unroll
    for (int j = 0; j < NT; ++j) acc[j] = (f32x4){0.f, 0.f, 0.f, 0.f};
    const __half* wsp = (const __half*)wsh;
    #pragma unroll
    for (int k0 = 0; k0 < K; k0 += 32) {
        f16x8 a;
        if (FP32IN) {
            const float* xr = (const float*)in_ + (m0 + lm) * K + k0 + q * 8;
            float4 x0 = ((const float4*)xr)[0];
            float4 x1 = ((const float4*)xr)[1];
            a = (f16x8){(_Float16)x0.x, (_Float16)x0.y, (_Float16)x0.z, (_Float16)x0.w,
                        (_Float16)x1.x, (_Float16)x1.y, (_Float16)x1.z, (_Float16)x1.w};
        } else {
            const __half* xr = (const __half*)in_ + (m0 + lm) * K + k0 + q * 8;
            a = *(const f16x8*)xr;
        }
        #pragma unroll
        for (int j = 0; j < NT; ++j) {
            f16x8 b = *(const f16x8*)(wsp + (16 * j + lm) * (2 * P2) + k0 + q * 8);
            acc[j] = __builtin_amdgcn_mfma_f32_16x16x32_f16(a, b, acc[j], 0, 0, 0);
        }
    }
    #pragma unroll
    for (int r = 0; r < 4; ++r) {
        long long m = m0 + q * 4 + r;
        float sc = SCALE ? dinv[m] : 1.0f;
        #pragma unroll
        for (int j = 0; j < NT; ++j) {
            int col = 16 * j + lm;
            if (col < OP) out[m * OP + col] = __float2half(acc[j][r] * sc);
        }
    }
}

// ---------------- launcher ----------------
static inline int cdiv(long long a, long long b) { return (int)((a + b - 1) / b); }
static inline size_t align256(size_t x) { return (x + 255) & ~(size_t)255; }

extern "C" void kernel_launch(void* const* d_in, const int* in_sizes, int n_in,
                              void* d_out, int out_size, void* d_ws, size_t ws_size,
                              hipStream_t stream) {
    const float* x  = (const float*)d_in[0];
    const void*  ei = d_in[1];
    const float* W0 = (const float*)d_in[2];
    const float* b0 = (const float*)d_in[3];
    const float* W4 = (const float*)d_in[4];
    const float* b4 = (const float*)d_in[5];
    float* out = (float*)d_out;

    const int N = N_NODES, E = N_EDGES;
    const int NB = cdiv(N, 256);  // 196
    char* ws = (char*)d_ws;
    int*    flag   = (int*)ws;     ws += 256;
    int*    deg    = (int*)ws;     ws += align256((size_t)N * 4);
    int*    rowptr = (int*)ws;     ws += align256((size_t)(N + 1) * 4);
    int*    cursor = (int*)ws;     ws += align256((size_t)N * 4);
    int*    part   = (int*)ws;     ws += align256(256 * 4);
    int*    bcnt   = (int*)ws;     ws += align256((size_t)NB * 64 * 4);
    int*    bbase  = (int*)ws;     ws += align256((size_t)NB * 64 * 4);
    int*    tot    = (int*)ws;     ws += align256(64 * 4);
    int*    qtail  = (int*)ws;     ws += align256(8 * 4);
    int*    perm   = (int*)ws;     ws += align256((size_t)N * 4);
    float*  dinv   = (float*)ws;   ws += align256((size_t)N * 4);
    int*    csrc   = (int*)ws;     ws += align256((size_t)E * 4);
    int2*   queue  = (int2*)ws;    ws += align256((size_t)8 * QCAP * 8);
    __half* bufA   = (__half*)ws;  ws += align256((size_t)N * HID_C * 2);
    __half* bufB   = (__half*)ws;  ws += align256((size_t)N * HID_C * 2);
    __half* bufC   = (__half*)ws;  ws += align256((size_t)N * HID_C * 2);

    const int T = 256;
    const int MT = N / 16;             // 3125 MFMA tiles
    const int LB = cdiv(MT, 4);        // mfma_lin blocks (4 waves each)
    const int P64B = cdiv(N, T / 8);   // prop64 blocks (32 groups each)
    const int P40B = cdiv(N, T / 8);   // prop40 blocks (32 groups each, 8 lanes)

    // ---- CSR build (two-phase partition queues) + degree sort ----
    zero_detect_k<<<cdiv(N, T), T, 0, stream>>>(deg, N, qtail, (const unsigned int*)ei, flag);
    bucketA_k<<<cdiv(E, 1024), T, 0, stream>>>(ei, flag, deg, qtail, queue, E);
    scan_p1_k<<<NB, 256, 0, stream>>>(deg, part, N);
    scan_p2_k<<<1, 256, 0, stream>>>(part, NB, rowptr, N);
    scan_p3_k<<<NB, 256, 0, stream>>>(deg, part, rowptr, cursor, dinv, bcnt, N);
    bscanA_k<<<64, 256, 0, stream>>>(bcnt, bbase, tot, NB);
    perm_k<<<NB, 256, 0, stream>>>(deg, bbase, tot, perm, N);
    bucketB_k<<<8 * 64, T, 0, stream>>>(qtail, queue, cursor, csrc);

    // ---- conv0 (SGConv, K=2): linear folded first; output G-space ----
    mfma_lin_k<HID_C, IN_C, HID_C, true, true><<<LB, 256, 0, stream>>>(x, W0, dinv, bufA, MT);
    prop64_k<false, false, false><<<P64B, T, 0, stream>>>(
        perm, rowptr, csrc, dinv, bufA, nullptr, nullptr, bufB, N);
    prop64_k<false, false, true><<<P64B, T, 0, stream>>>(
        perm, rowptr, csrc, dinv, bufB, nullptr, b0, bufC, N);  // + dinv*b0 -> Gh0

    // ---- conv1..conv3: leaky(APPNP(h)) entirely in G-space, Gh0 = bufC ----
    for (int r = 0; r < 3; ++r) {
        prop64_k<true, false, false><<<P64B, T, 0, stream>>>(
            perm, rowptr, csrc, dinv, bufC, bufC, nullptr, bufB, N);
        // in-place bufC write safe: Gh0[node] read only by the group writing it
        prop64_k<true, true, false><<<P64B, T, 0, stream>>>(
            perm, rowptr, csrc, dinv, bufB, bufC, nullptr, bufC, N);
    }

    // ---- conv4 (SGConv, K=2): G-space lin (no scale, padded 128 B rows),
    // then 2 hops at 40ch ----
    mfma_lin_k<OUT_C, HID_C, HID_C, false, false><<<LB, 256, 0, stream>>>(
        bufC, W4, dinv, bufA, MT);
    prop40_k<<<P40B, T, 0, stream>>>(perm, rowptr, csrc, dinv, bufA, bufB, N);
    prop40_softmax_k<<<P40B, T, 0, stream>>>(perm, rowptr, csrc, dinv, bufB, b4, out, N);
}